// Round 6
// baseline (146.080 us; speedup 1.0000x reference)
//
#include <hip/hip_runtime.h>
#include <stdint.h>

// B=1, R=128, L=256, IN=128, DM=32, DIM=128
// out[i,j,k] = x[i,j,k] + (1/R)*sum_{r,c,d} mp[r,j,c]*mp[r,i,d]*W2[k,c*32+d] + b2[k]
// mp[r,i,d]  = sum_e m[r,i,e]*W1[d,e] + b1[d]
//
// mpF[rt][kr][lane][j]  rt=(i*32+d)>>4 (512), kr=r>>5 (4):
//     value mp[r = kr*32 + (lane>>4)*8 + j][row = rt*16 + (lane&15)]
// W2f[nt][kc][lane][j]  nt=kout>>4 (8), kc=d (32):
//     value W2t[kout=nt*16+(lane&15)][cd' = kc*32 + (lane>>4)*8 + j]
// Block = 8i x 8j (64 pairs), 1024 blocks, 4 (j-half, d-half) segments.
// stepB: wave tile 64m x 32n (4am x 2bn): A global (L1 catches 4x dup),
//        B from LDS Bs (dup-free staging).
// stepC: kloc-split — wave w: kloc-half h=w>>2, kout-tiles 2(w&3), 2(w&3)+1.
//        G LDS reads halved vs kout-per-wave layout; partials merged in
//        f32 epilogue (h0 write, h1 add).

typedef __attribute__((ext_vector_type(8))) short bf16x8;
typedef __attribute__((ext_vector_type(4))) float f32x4;

#define MFMA16 __builtin_amdgcn_mfma_f32_16x16x32_bf16

__device__ __forceinline__ unsigned short f2bf(float f) {
    union { float f; unsigned int u; } x; x.f = f;
    unsigned int r = (x.u + 0x7fffu + ((x.u >> 16) & 1u)) >> 16;  // RNE
    return (unsigned short)r;
}

__device__ __forceinline__ bf16x8 load8f_bf(const float* p) {
    float4 v0 = *(const float4*)p;
    float4 v1 = *(const float4*)(p + 4);
    union { bf16x8 v; unsigned short u[8]; } r;
    r.u[0] = f2bf(v0.x); r.u[1] = f2bf(v0.y); r.u[2] = f2bf(v0.z); r.u[3] = f2bf(v0.w);
    r.u[4] = f2bf(v1.x); r.u[5] = f2bf(v1.y); r.u[6] = f2bf(v1.z); r.u[7] = f2bf(v1.w);
    return r.v;
}

// ---------------------------------------------------------------------------
// prep: blocks 0..511 -> mp GEMM -> mpF; blocks 512..575 -> W2 -> W2f
// ---------------------------------------------------------------------------
__global__ __launch_bounds__(256) void prep_kernel(
    const float* __restrict__ m, const float* __restrict__ W1,
    const float* __restrict__ pb1, const float* __restrict__ W2,
    unsigned short* __restrict__ mpF, unsigned short* __restrict__ W2f)
{
    const int bx = blockIdx.x;
    if (bx >= 512) {
        const int t    = (bx - 512) * 256 + threadIdx.x;   // 0..16383
        const int nt   = t >> 11;
        const int kc   = (t >> 6) & 31;
        const int lane = t & 63;
        const int ln   = lane & 15, q = lane >> 4;
        const float* src = W2 + (size_t)(nt * 16 + ln) * 1024 + kc;
        union { bf16x8 v; unsigned short u[8]; } r;
        #pragma unroll
        for (int j = 0; j < 8; ++j)
            r.u[j] = f2bf(src[(q * 8 + j) * 32]);
        *(bf16x8*)(W2f + (size_t)t * 8) = r.v;
        return;
    }
    const int lane = threadIdx.x & 63;
    const int w    = threadIdx.x >> 6;
    const int ln   = lane & 15, q = lane >> 4;
    const int tile = bx * 4 + w;          // 0..2047
    const int i    = tile >> 3;           // 0..255
    const int r0   = (tile & 7) * 16;     // r-tile base

    const float* Ap  = m  + ((size_t)(r0 + ln) * 256 + i) * 128 + q * 8;
    const float* Bp0 = W1 + (size_t)ln * 128 + q * 8;
    const float* Bp1 = W1 + (size_t)(16 + ln) * 128 + q * 8;

    f32x4 acc0 = {0.f, 0.f, 0.f, 0.f};
    f32x4 acc1 = {0.f, 0.f, 0.f, 0.f};
    #pragma unroll
    for (int ke = 0; ke < 4; ++ke) {
        bf16x8 a  = load8f_bf(Ap  + ke * 32);
        bf16x8 b0 = load8f_bf(Bp0 + ke * 32);
        bf16x8 b1 = load8f_bf(Bp1 + ke * 32);
        acc0 = MFMA16(a, b0, acc0, 0, 0, 0);
        acc1 = MFMA16(a, b1, acc1, 0, 0, 0);
    }
    const float bb0 = pb1[ln];
    const float bb1 = pb1[16 + ln];
    const int kr = r0 >> 5;
    const int qr = ((r0 >> 4) & 1) * 2 + (q >> 1);
    const int j0 = (q & 1) * 4;
    const size_t off0 = (size_t)(i * 2 + 0) * 2048 + kr * 512 + (qr * 16 + ln) * 8 + j0;
    const size_t off1 = (size_t)(i * 2 + 1) * 2048 + kr * 512 + (qr * 16 + ln) * 8 + j0;
    ushort4 o0, o1;
    o0.x = f2bf(acc0[0] + bb0); o0.y = f2bf(acc0[1] + bb0);
    o0.z = f2bf(acc0[2] + bb0); o0.w = f2bf(acc0[3] + bb0);
    o1.x = f2bf(acc1[0] + bb1); o1.y = f2bf(acc1[1] + bb1);
    o1.z = f2bf(acc1[2] + bb1); o1.w = f2bf(acc1[3] + bb1);
    *(ushort4*)(mpF + off0) = o0;
    *(ushort4*)(mpF + off1) = o1;
}

// ---------------------------------------------------------------------------
// fused helpers
// ---------------------------------------------------------------------------
__device__ __forceinline__ void stage_load(const unsigned short* __restrict__ mpF,
                                           int i0, int dhalf, int tid, uint4 (&stg)[4])
{
    #pragma unroll
    for (int r = 0; r < 4; ++r) {
        const int cid = r * 512 + tid;            // 0..2047 (16B chunks)
        const int it  = cid >> 8;                 // i-slot 0..7
        const int pos = cid & 255;                // 16B unit within 4KB row
        stg[r] = *(const uint4*)(mpF + (size_t)((i0 + it) * 2 + dhalf) * 2048 + pos * 8);
    }
}

__device__ __forceinline__ void stage_store(unsigned short* __restrict__ Bs,
                                            int tid, const uint4 (&stg)[4])
{
    #pragma unroll
    for (int r = 0; r < 4; ++r) {
        const int cid = r * 512 + tid;
        const int it  = cid >> 8;
        const int pos = cid & 255;
        *(uint4*)(Bs + it * 2048 + pos * 8) = stg[r];   // linear -> conflict-free
    }
}

// stepB: wave tile 64m x 32n. m = wm*64 + am*16 (tj = wm*2+(am>>1),
// c-half = am&1); n = wn*32 + bn*16 (ti = wn*2+bn, d''=ln).
__device__ __forceinline__ void stepB6(const unsigned short* __restrict__ mpF,
                                       const unsigned short* __restrict__ Bs,
                                       int j0, int jh, int wm, int wn, int lane,
                                       f32x4 (&acc)[4][2])
{
    #pragma unroll
    for (int a = 0; a < 4; ++a)
        #pragma unroll
        for (int b = 0; b < 2; ++b)
            acc[a][b] = (f32x4){0.f, 0.f, 0.f, 0.f};
    #pragma unroll
    for (int ks = 0; ks < 4; ++ks) {
        bf16x8 av[4], bv[2];
        #pragma unroll
        for (int am = 0; am < 4; ++am) {
            const int rt = (j0 + jh * 4 + wm * 2 + (am >> 1)) * 2 + (am & 1);
            av[am] = *(const bf16x8*)(mpF + (size_t)rt * 2048 + ks * 512 + lane * 8);
        }
        #pragma unroll
        for (int bn = 0; bn < 2; ++bn)
            bv[bn] = *(const bf16x8*)(Bs + (lane & 512 ? 0 : 0) + ((0) ) + ( ( ( (bn) + 0) ) * 0 ) + ( ( ( ( (0) ) ) ) ) + ( ( ( ( ( ( (int)0 ) ) ) ) ) ) + ( ( ( ( ( ( ( ( (int)((0)) ) ) ) ) ) ) ) ) + ( ( ( ( ( ( ( (0) ) ) ) ) ) ) ) + ( ( ( ( (0) ) ) ) ) + ( ( ( (0) ) ) ) + ( ( (0) ) ) + ( (0) ) + (0) + ( ( ( ( ( ( ( ( ( (0) ) ) ) ) ) ) ) ) ) + 0 );
        // (placeholder removed below)
        (void)bv;
        break;
    }
    // real implementation below (kept separate to avoid the macro confusion)
}

// NOTE: stepB6 above is superseded by stepB6r — see below. (stepB6 unused.)
__device__ __forceinline__ void stepB6r(const unsigned short* __restrict__ mpF,
                                        const unsigned short* __restrict__ Bs,
                                        int j0, int jh, int wm, int wn, int lane,
                                        f32x4 (&acc)[4][2])
{
    #pragma unroll
    for (int a = 0; a < 4; ++a)
        #pragma unroll
        for (int b = 0; b < 2; ++b)
            acc[a][b] = (f32x4){0.f, 0.f, 0.f, 0.f};
    #pragma unroll
    for (int ks = 0; ks < 4; ++ks) {
        bf16x8 av[4], bv[2];
        #pragma unroll
        for (int am = 0; am < 4; ++am) {
            const int rt = (j0 + jh * 4 + wm * 2 + (am >> 1)) * 2 + (am & 1);
            av[am] = *(const bf16x8*)(mpF + (size_t)rt * 2048 + ks * 512 + lane * 8);
        }
        #pragma unroll
        for (int bn = 0; bn < 2; ++bn)
            bv[bn] = *(const bf16x8*)(Bs + (wn * 2 + bn) * 2048 + ks * 512 + lane * 8);
        #pragma unroll
        for (int am = 0; am < 4; ++am)
            #pragma unroll
            for (int bn = 0; bn < 2; ++bn)
                acc[am][bn] = MFMA16(av[am], bv[bn], acc[am][bn], 0, 0, 0);
    }
}

// G -> LDS: p = ti*4+tj, kloc = d''*32 + c; chunk = kloc>>3;
// addr_h = chunk*256 + (p^(chunk>>3))*8 + (kloc&7)
__device__ __forceinline__ void gwrite6(unsigned short* __restrict__ Gl,
                                        const f32x4 (&acc)[4][2],
                                        int ln, int q, int wm, int wn)
{
    #pragma unroll
    for (int am = 0; am < 4; ++am) {
        const int chunk = ln * 4 + (am & 1) * 2 + (q >> 1);
        const int sig   = chunk >> 3;
        const int hbase = chunk * 256 + (q & 1) * 4;
        #pragma unroll
        for (int bn = 0; bn < 2; ++bn) {
            const int p  = (wn * 2 + bn) * 4 + wm * 2 + (am >> 1);
            const int pp = p ^ sig;
            ushort4 g;
            g.x = f2bf(acc[am][bn][0]); g.y = f2bf(acc[am][bn][1]);
            g.z = f2bf(acc[am][bn][2]); g.w = f2bf(acc[am][bn][3]);
            *(ushort4*)(Gl + hbase + pp * 8) = g;
        }
    }
}

// stepC (kloc-split): wave covers kout-tiles ntA, ntA+1 over kloc-half h.
__device__ __forceinline__ void stepC6(const unsigned short* __restrict__ Gl,
                                       const unsigned short* __restrict__ wpA,
                                       const unsigned short* __restrict__ wpB,
                                       int h, int ln, int q,
                                       f32x4& c00, f32x4& c01, f32x4& c10, f32x4& c11)
{
    bf16x8 wa = *(const bf16x8*)wpA;
    bf16x8 wb = *(const bf16x8*)wpB;
    #pragma unroll
    for (int ks = 0; ks < 8; ++ks) {
        const int chunk = h * 32 + ks * 4 + q;
        const int sig   = h * 4 + (ks >> 1);
        const unsigned short* gp = Gl + chunk * 256 + ((ln ^ sig) << 3);
        bf16x8 ag0 = *(const bf16x8*)gp;          // pairs 0..15
        bf16x8 ag1 = *(const bf16x8*)(gp + 128);  // pairs 16..31
        bf16x8 ca = wa, cb = wb;
        if (ks < 7) {
            wa = *(const bf16x8*)(wpA + (ks + 1) * 512);
            wb = *(const bf16x8*)(wpB + (ks + 1) * 512);
        }
        c00 = MFMA16(ag0, ca, c00, 0, 0, 0);
        c10 = MFMA16(ag1, ca, c10, 0, 0, 0);
        c01 = MFMA16(ag0, cb, c01, 0, 0, 0);
        c11 = MFMA16(ag1, cb, c11, 0, 0, 0);
    }
}

// ---------------------------------------------------------------------------
// fused: block = 8i x 8j (64 pairs), 4 segments (j-half x d-half).
// ---------------------------------------------------------------------------
__global__ __launch_bounds__(512, 4) void fused_kernel(
    const float* __restrict__ x, const float* __restrict__ b2,
    const unsigned short* __restrict__ mpF, const unsigned short* __restrict__ W2f,
    float* __restrict__ out)
{
    __shared__ __align__(16) unsigned char smem[65536];
    unsigned short* Gl = (unsigned short*)smem;            // 64 chunks x 256 shorts
    unsigned short* Bs = (unsigned short*)(smem + 32768);  // 8 i x 2048 shorts

    const int tid  = threadIdx.x;
    const int lane = tid & 63, w = tid >> 6;
    const int ln   = lane & 15, q = lane >> 4;
    const int wm   = w & 1, wn = (w >> 1) & 3;   // stepB wave grid 2m x 4n
    const int h    = w >> 2;                     // stepC kloc-half
    const int kt4  = w & 3;                      // stepC kout-tile pair idx

    const int i0 = blockIdx.x * 8;               // gridDim.x = 32
    const int j0 = blockIdx.y * 8;               // gridDim.y = 32

    // cacc[jh][pg][kt]
    f32x4 cacc[2][2][2];
    #pragma unroll
    for (int a = 0; a < 2; ++a)
        #pragma unroll
        for (int b = 0; b < 2; ++b)
            #pragma unroll
            for (int c = 0; c < 2; ++c)
                cacc[a][b][c] = (f32x4){0.f, 0.f, 0.f, 0.f};

    f32x4 acc[4][2];
    uint4 stg[4];

    // W2 bases: nt = kt4*2 (+1); kc = pass*16 + h*8 + ks
    const unsigned short* wA0 = W2f + (size_t)((kt4 * 2) * 32 + h * 8) * 512 + lane * 8;
    const unsigned short* wB0 = wA0 + (size_t)32 * 512;
    const unsigned short* wA1 = wA0 + (size_t)16 * 512;    // pass 1 (+16 kc)
    const unsigned short* wB1 = wB0 + (size_t)16 * 512;

    // ---- stage Bs(d0) ----
    stage_load(mpF, i0, 0, tid, stg);
    stage_store(Bs, tid, stg);
    __syncthreads();                                   // S1: Bs(d0) ready

    // ---- seg0 (j0, d0) ----
    stepB6r(mpF, Bs, j0, 0, wm, wn, lane, acc);
    gwrite6(Gl, acc, ln, q, wm, wn);
    __syncthreads();                                   // S2: Gl ready
    stepC6(Gl, wA0, wB0, h, ln, q,
           cacc[0][0][0], cacc[0][0][1], cacc[0][1][0], cacc[0][1][1]);
    stepB6r(mpF, Bs, j0, 1, wm, wn, lane, acc);        // seg1 stepB (regs only)
    __syncthreads();                                   // S3: Gl reads done
    gwrite6(Gl, acc, ln, q, wm, wn);
    __syncthreads();                                   // S4: Gl ready
    stage_load(mpF, i0, 1, tid, stg);                  // d1 staging loads in flight
    stepC6(Gl, wA0, wB0, h, ln, q,
           cacc[1][0][0], cacc[1][0][1], cacc[1][1][0], cacc[1][1][1]);
    stage_store(Bs, tid, stg);                         // Bs(d0) readers done at S3
    __syncthreads();                                   // S5: Bs(d1) ready + Gl free

    // ---- seg2 (j0, d1) ----
    stepB6r(mpF, Bs, j0, 0, wm, wn, lane, acc);
    gwrite6(Gl, acc, ln, q, wm, wn);
    __syncthreads();                                   // S6: Gl ready
    stepC6(Gl, wA1, wB1, h, ln, q,
           cacc[0][0][0], cacc[0][0][1], cacc[0][1][0], cacc[0][1][1]);
    stepB6r(mpF, Bs, j0, 1, wm, wn, lane, acc);        // seg3 stepB
    __syncthreads();                                   // S7: Gl reads done
    gwrite6(Gl, acc, ln, q, wm, wn);
    __syncthreads();                                   // S8: Gl ready

    // prefetch x while last stepC runs
    float4 xv[4];
    size_t gb[4];
    #pragma unroll
    for (int e = 0; e < 4; ++e) {
        const int fid = e * 512 + tid;                 // 0..2047 float4 units
        const int po  = fid >> 5, kq = fid & 31;
        gb[e] = ((size_t)(i0 + (po >> 3)) * 256 + (j0 + (po & 7))) * 128 + kq * 4;
        xv[e] = *(const float4*)(x + gb[e]);
    }

    stepC6(Gl, wA1, wB1, h, ln, q,
           cacc[1][0][0], cacc[1][0][1], cacc[1][1][0], cacc[1][1][1]);
    __syncthreads();                                   // S9: Gl free -> Ep

    // ---- epilogue: merge kloc-halves in f32, coalesced out ----
    float* Ep = (float*)smem;                          // 64 rows x 128 floats (32 KB)
    const float invR = 1.0f / 128.0f;
    if (h == 0) {
        #pragma unroll
        for (int jh = 0; jh < 2; ++jh)
            #pragma unroll
            for (int pg = 0; pg < 2; ++pg)
                #pragma unroll
                for (int kt = 0; kt < 2; ++kt)
                    #pragma unroll
                    for (int rg = 0; rg < 4; ++rg) {
                        const int po  = (pg * 4 + q) * 8 + jh * 4 + rg;
                        const int col = (kt4 * 2 + kt) * 16 + ln;
                        const int u   = col >> 2;
                        Ep[po * 128 + ((u ^ (po & 7)) << 2) + (col & 3)] =
                            cacc[jh][pg][kt][rg] * invR;
                    }
    }
    __syncthreads();                                   // S10: h0 written
    if (h == 1) {
        #pragma unroll
        for (int jh = 0; jh < 2; ++jh)
            #pragma unroll
            for (int pg = 0; pg < 2; ++pg)
                #pragma unroll
                for (int kt = 0; kt < 2; ++kt)
                    #pragma unroll
                    for (int rg = 0; rg < 4; ++rg) {
                        const int po  = (pg * 4 + q) * 8 + jh * 4 + rg;
                        const int col = (kt4 * 2 + kt) * 16 + ln;
                        const int u   = col >> 2;
                        Ep[po * 128 + ((u ^ (po & 7)) << 2) + (col & 3)] +=
                            cacc[jh][pg][kt][rg] * invR;
                    }
    }
    __syncthreads();                                   // S11: merged

    #pragma unroll
    for (int e = 0; e < 4; ++e) {
        const int fid = e * 512 + tid;
        const int po  = fid >> 5, kq = fid & 31;
        const float4 v  = *(const float4*)(Ep + po * 128 + ((kq ^ (po & 7)) << 2));
        const float4 bv = *(const float4*)(b2 + kq * 4);
        float4 o;
        o.x = xv[e].x + v.x + bv.x; o.y = xv[e].y + v.y + bv.y;
        o.z = xv[e].z + v.z + bv.z; o.w = xv[e].w + v.w + bv.w;
        *(float4*)(out + gb[e]) = o;
    }
}

extern "C" void kernel_launch(void* const* d_in, const int* in_sizes, int n_in,
                              void* d_out, int out_size, void* d_ws, size_t ws_size,
                              hipStream_t stream) {
    const float* x  = (const float*)d_in[0];
    const float* m  = (const float*)d_in[1];
    const float* W1 = (const float*)d_in[2];
    const float* b1 = (const float*)d_in[3];
    const float* W2 = (const float*)d_in[4];
    const float* b2 = (const float*)d_in[5];
    float* out = (float*)d_out;

    unsigned short* mpF = (unsigned short*)d_ws;               // 512*2048 h = 2 MB
    unsigned short* W2f = mpF + (size_t)512 * 2048;            // 131072 h = 256 KB

    prep_kernel<<<dim3(576), dim3(256), 0, stream>>>(m, W1, b1, W2, mpF, W2f);
    fused_kernel<<<dim3(32, 32), dim3(512), 0, stream>>>(x, b2, mpF, W2f, out);
}